// Round 8
// baseline (375.603 us; speedup 1.0000x reference)
//
#include <hip/hip_runtime.h>
#include <hip/hip_bf16.h>

#define Bb 4
#define Cc 256
#define Nn 4096

typedef short s16x8 __attribute__((ext_vector_type(8)));
typedef float f32x4 __attribute__((ext_vector_type(4)));

__device__ __forceinline__ unsigned short f2bf(float f) {
    unsigned u = __builtin_bit_cast(unsigned, f);
    u += 0x7FFFu + ((u >> 16) & 1u);
    return (unsigned short)(u >> 16);
}

__device__ __forceinline__ f32x4 mfma16(s16x8 a, s16x8 b, f32x4 c) {
    return __builtin_amdgcn_mfma_f32_16x16x32_bf16(a, b, c, 0, 0, 0);
}

#if __has_builtin(__builtin_amdgcn_global_load_lds)
#define GL16(g, sdst)                                                              \
    __builtin_amdgcn_global_load_lds(                                              \
        (const __attribute__((address_space(1))) unsigned int*)(g),                \
        (__attribute__((address_space(3))) unsigned int*)(sdst), 16, 0, 0)
#else
#define GL16(g, sdst)                                                              \
    do {                                                                           \
        *(s16x8*)((char*)(sdst) + (threadIdx.x & 63) * 16) = *(const s16x8*)(g);   \
    } while (0)
#endif

// ---------------- prep: W fp32 -> bf16 ----------------
__global__ void prep_w(const float* __restrict__ Wq, const float* __restrict__ Wk,
                       const float* __restrict__ Wv, unsigned short* __restrict__ Wbf) {
    int idx = (blockIdx.x * 256 + threadIdx.x) * 8;  // < 3*65536
    int mat = idx >> 16;
    int off = idx & 65535;
    const float* src = (mat == 0) ? Wq : ((mat == 1) ? Wk : Wv);
    float4 a = *(const float4*)(src + off);
    float4 b = *(const float4*)(src + off + 4);
    s16x8 o;
    o[0] = (short)f2bf(a.x); o[1] = (short)f2bf(a.y);
    o[2] = (short)f2bf(a.z); o[3] = (short)f2bf(a.w);
    o[4] = (short)f2bf(b.x); o[5] = (short)f2bf(b.y);
    o[6] = (short)f2bf(b.z); o[7] = (short)f2bf(b.w);
    *(s16x8*)(Wbf + idx) = o;
}

// ---------------- transpose: x[b][c][n] fp32 -> xT[b][n][c] bf16 ----------------
__global__ void transpose_x(const float* __restrict__ x, unsigned short* __restrict__ xT) {
    int b = blockIdx.z, c0 = blockIdx.y * 64, n0 = blockIdx.x * 64;
    __shared__ float tile[64][65];
    int t = threadIdx.x;
    int r = t >> 2, q = t & 3;
    const float* src = x + ((size_t)(b * Cc + c0 + r)) * Nn + n0 + q * 16;
#pragma unroll
    for (int j = 0; j < 4; j++) {
        float4 v4 = *(const float4*)(src + j * 4);
        tile[r][q * 16 + j * 4 + 0] = v4.x;
        tile[r][q * 16 + j * 4 + 1] = v4.y;
        tile[r][q * 16 + j * 4 + 2] = v4.z;
        tile[r][q * 16 + j * 4 + 3] = v4.w;
    }
    __syncthreads();
    unsigned short* dst = xT + ((size_t)b * Nn + n0 + r) * Cc + c0 + q * 16;
    s16x8 o0, o1;
#pragma unroll
    for (int j = 0; j < 8; j++) o0[j] = (short)f2bf(tile[q * 16 + j][r]);
#pragma unroll
    for (int j = 0; j < 8; j++) o1[j] = (short)f2bf(tile[q * 16 + 8 + j][r]);
    *(s16x8*)dst = o0;
    *(s16x8*)(dst + 8) = o1;
}

// ---------------- projections ----------------
__global__ void proj(const unsigned short* __restrict__ xT, const unsigned short* __restrict__ Wbf,
                     const float* __restrict__ bq, const float* __restrict__ bk,
                     const float* __restrict__ bv,
                     unsigned short* __restrict__ qT, unsigned short* __restrict__ kT,
                     unsigned short* __restrict__ vO) {
    int nt0 = blockIdx.x * 64;
    int mat = blockIdx.y;
    int b   = blockIdx.z;
    int t = threadIdx.x, w = t >> 6, l = t & 63;
    int lr = l & 15, lg = l >> 4;
    const unsigned short* Wm  = Wbf + mat * (Cc * Cc);
    const float* bias = (mat == 0) ? bq : ((mat == 1) ? bk : bv);
    const unsigned short* xTb = xT + (size_t)b * Nn * Cc;

    if (mat < 2) {
        unsigned short* out = ((mat == 0) ? qT : kT) + (size_t)b * Nn * Cc;
        int nrow = nt0 + w * 16;
        s16x8 af[8];
#pragma unroll
        for (int kk = 0; kk < 8; kk++)
            af[kk] = *(const s16x8*)(xTb + (nrow + lr) * Cc + kk * 32 + lg * 8);
        for (int ct = 0; ct < 16; ct++) {
            f32x4 acca = {0, 0, 0, 0}, accb = {0, 0, 0, 0};
#pragma unroll
            for (int kk = 0; kk < 8; kk += 2) {
                s16x8 bfa = *(const s16x8*)(Wm + (ct * 16 + lr) * Cc + kk * 32 + lg * 8);
                s16x8 bfb = *(const s16x8*)(Wm + (ct * 16 + lr) * Cc + (kk + 1) * 32 + lg * 8);
                acca = mfma16(af[kk], bfa, acca);
                accb = mfma16(af[kk + 1], bfb, accb);
            }
            f32x4 acc = acca + accb;
            float bb = bias[ct * 16 + lr];
#pragma unroll
            for (int r = 0; r < 4; r++)
                out[(nrow + lg * 4 + r) * Cc + ct * 16 + lr] = f2bf(acc[r] + bb);
        }
    } else {
        unsigned short* out = vO + (size_t)b * Cc * Nn;
        for (int mt = 0; mt < 4; mt++) {
            int crow = (w * 4 + mt) * 16;
            s16x8 af[8];
#pragma unroll
            for (int kk = 0; kk < 8; kk++)
                af[kk] = *(const s16x8*)(Wm + (crow + lr) * Cc + kk * 32 + lg * 8);
#pragma unroll
            for (int nt = 0; nt < 4; nt++) {
                f32x4 acca = {0, 0, 0, 0}, accb = {0, 0, 0, 0};
#pragma unroll
                for (int kk = 0; kk < 8; kk += 2) {
                    s16x8 bfa = *(const s16x8*)(xTb + (nt0 + nt * 16 + lr) * Cc + kk * 32 + lg * 8);
                    s16x8 bfb = *(const s16x8*)(xTb + (nt0 + nt * 16 + lr) * Cc + (kk + 1) * 32 + lg * 8);
                    acca = mfma16(af[kk], bfa, acca);
                    accb = mfma16(af[kk + 1], bfb, accb);
                }
                f32x4 acc = acca + accb;
#pragma unroll
                for (int r = 0; r < 4; r++) {
                    float bb = bias[crow + lg * 4 + r];
                    out[(size_t)(crow + lg * 4 + r) * Nn + nt0 + nt * 16 + lr] = f2bf(acc[r] + bb);
                }
            }
        }
    }
}

// ---------------- fused flash attention, c-split wave pairs ----------------
// 512 blocks x 512 threads, 2 blocks/CU => 4 waves/SIMD of INDEPENDENT blocks
// (barrier in one block doesn't stall the other => real TLP).
// id&7 = (b,s) combo as R5/R7: one combo per XCD (1MB K + 1MB V L2-resident,
// 64 lockstep blocks). Block = 64 i-rows; 8 waves = 4 row-teams x 2 c-teams.
// Each wave: full QK^T for its 16 rows (E duplicated across the c-team pair),
// PV over its 128-channel half of V (halves per-wave V traffic).
// K tile LDS dbuf (global_load_lds, (row&7)<<4 XOR both sides).
// Co-resident blocks share the same K/V stream -> L1 reuse.
__global__ void __launch_bounds__(512, 4)
attn(const unsigned short* __restrict__ qT, const unsigned short* __restrict__ kT,
     const unsigned short* __restrict__ vv,
     float* __restrict__ OPT, float* __restrict__ lp) {
    int id = blockIdx.x;
    int bs = id & 7, b = bs >> 1, s = bs & 1, iblk = id >> 3;  // iblk 0..63
    int t = threadIdx.x, w = t >> 6, l = t & 63;
    int lr = l & 15, lg = l >> 4;
    int rt = w >> 1, cteam = w & 1;
    int i0 = iblk * 64 + rt * 16;

    __shared__ char Ks[2][16384];               // K tile dbuf: 32 rows x 512B
    __shared__ unsigned short P_lds[8][512];    // per-wave [16][32] bf16

    unsigned short* pl = P_lds[w];
    const unsigned short* qb = qT + ((size_t)b * Nn + i0) * Cc;
    const char* kbase = (const char*)(kT + ((size_t)b * Nn + s * 2048) * Cc);
    const unsigned short* vbase = vv + ((size_t)b * Cc + cteam * 128) * Nn + s * 2048;

    s16x8 qf[8];
#pragma unroll
    for (int kk = 0; kk < 8; kk++)
        qf[kk] = *(const s16x8*)(qb + lr * Cc + kk * 32 + lg * 8);

    f32x4 O[8];
#pragma unroll
    for (int ct = 0; ct < 8; ct++) O[ct] = {0, 0, 0, 0};
    float lsum[4] = {0, 0, 0, 0};
    const float L2E = 1.44269504088896340736f;

// stage 16KB K tile (32 rows x 512B); 16 chunks of 1KB; wave w covers w*2,w*2+1
#define STAGEK(bufi, jt)                                                        \
    {                                                                           \
        const char* ksl_ = kbase + (size_t)(jt) * 16384;                        \
        _Pragma("unroll") for (int i_ = 0; i_ < 2; i_++) {                      \
            int chunk_ = w * 2 + i_;                                            \
            int L_ = chunk_ * 1024 + l * 16;                                    \
            int row_ = L_ >> 9;                                                 \
            GL16(ksl_ + (L_ ^ ((row_ & 7) << 4)), &Ks[bufi][chunk_ * 1024]);    \
        }                                                                       \
    }

    STAGEK(0, 0);
    asm volatile("s_waitcnt vmcnt(0)" ::: "memory");
    __syncthreads();
    int buf = 0;

    for (int jt = 0; jt < 64; jt++) {
        int j0 = jt * 32;
        // ---- prefetch next K tile into other buffer ----
        if (jt < 63) STAGEK(buf ^ 1, jt + 1);
        // ---- QK^T from K-LDS (full 256-c reduction, all waves) ----
        const char* ksb = Ks[buf];
        f32x4 E0 = {0, 0, 0, 0}, E1 = {0, 0, 0, 0};
        __builtin_amdgcn_s_setprio(1);
#pragma unroll
        for (int kk = 0; kk < 8; kk++) {
            int cb = (kk * 64 + lg * 16) ^ ((lr & 7) << 4);
            s16x8 k0 = *(const s16x8*)(ksb + lr * 512 + cb);
            s16x8 k1 = *(const s16x8*)(ksb + (16 + lr) * 512 + cb);
            E0 = mfma16(qf[kk], k0, E0);
            E1 = mfma16(qf[kk], k1, E1);
        }
        __builtin_amdgcn_s_setprio(0);
        // ---- shift-free softmax ----
        float p0[4], p1[4];
#pragma unroll
        for (int r = 0; r < 4; r++) {
            p0[r] = exp2f(E0[r] * L2E);
            p1[r] = exp2f(E1[r] * L2E);
            lsum[r] += p0[r] + p1[r];
        }
        // ---- P -> bf16 -> LDS roundtrip (wave-synchronous, proven layout) ----
#pragma unroll
        for (int r = 0; r < 4; r++) {
            pl[(lg * 4 + r) * 32 + lr] = f2bf(p0[r]);
            pl[(lg * 4 + r) * 32 + 16 + lr] = f2bf(p1[r]);
        }
        asm volatile("s_waitcnt lgkmcnt(0)" ::: "memory");
        __builtin_amdgcn_sched_barrier(0);
        s16x8 pf = *(const s16x8*)(pl + lr * 32 + lg * 8);
        // ---- PV over this wave's 128-channel half (just-in-time V loads) ----
        __builtin_amdgcn_s_setprio(1);
#pragma unroll
        for (int h = 0; h < 2; h++) {
            s16x8 vf[4];
#pragma unroll
            for (int c4 = 0; c4 < 4; c4++)
                vf[c4] = *(const s16x8*)(vbase + (size_t)((h * 4 + c4) * 16 + lr) * Nn + j0 + lg * 8);
#pragma unroll
            for (int c4 = 0; c4 < 4; c4++)
                O[h * 4 + c4] = mfma16(pf, vf[c4], O[h * 4 + c4]);
        }
        __builtin_amdgcn_s_setprio(0);
        asm volatile("s_waitcnt vmcnt(0)" ::: "memory");
        __syncthreads();
        buf ^= 1;
    }

    // ---- l reduction across 16 lanes of each row group ----
#pragma unroll
    for (int r = 0; r < 4; r++) {
#pragma unroll
        for (int msk = 1; msk <= 8; msk <<= 1)
            lsum[r] += __shfl_xor(lsum[r], msk);
    }
    size_t sb = (size_t)(s * Bb + b);
    if (cteam == 0 && lr == 0) {
#pragma unroll
        for (int r = 0; r < 4; r++)
            lp[sb * Nn + i0 + lg * 4 + r] = lsum[r];
    }
    // ---- fp32 partials, [n][c] layout: 16 lr lanes contiguous in c ----
    float* ob = OPT + sb * Nn * Cc;
#pragma unroll
    for (int ct = 0; ct < 8; ct++) {
#pragma unroll
        for (int r = 0; r < 4; r++)
            ob[(size_t)(i0 + lg * 4 + r) * Cc + cteam * 128 + ct * 16 + lr] = O[ct][r];
    }
#undef STAGEK
}

// ---------------- merge partials + transpose + epilogue ----------------
// out[b][c][n] = gamma * (OPT0+OPT1)[n][c] / (l0+l1)[n] + x[b][c][n]
__global__ void __launch_bounds__(256)
merge(const float* __restrict__ OPT, const float* __restrict__ lp,
      const float* __restrict__ x, const float* __restrict__ gamma,
      float* __restrict__ out) {
    int b = blockIdx.z, c0 = blockIdx.y * 64, n0 = blockIdx.x * 64;
    __shared__ float tile[64][65];
    __shared__ float linv[64];
    int t = threadIdx.x;
    if (t < 64) {
        float sum = lp[(size_t)b * Nn + n0 + t] + lp[(size_t)(Bb + b) * Nn + n0 + t];
        linv[t] = 1.0f / sum;
    }
    __syncthreads();
    float g = gamma[0];
    int r = t >> 2, q = t & 3;
    const float* p0 = OPT + ((size_t)b * Nn + n0 + r) * Cc + c0 + q * 16;
    const float* p1 = OPT + ((size_t)(Bb + b) * Nn + n0 + r) * Cc + c0 + q * 16;
    float sc = g * linv[r];
#pragma unroll
    for (int j = 0; j < 4; j++) {
        float4 a0 = *(const float4*)(p0 + j * 4);
        float4 a1 = *(const float4*)(p1 + j * 4);
        tile[r][q * 16 + j * 4 + 0] = sc * (a0.x + a1.x);
        tile[r][q * 16 + j * 4 + 1] = sc * (a0.y + a1.y);
        tile[r][q * 16 + j * 4 + 2] = sc * (a0.z + a1.z);
        tile[r][q * 16 + j * 4 + 3] = sc * (a0.w + a1.w);
    }
    __syncthreads();
    // write rows of out: row c = c0 + r, cols n0 + q*16 .. +15
    const float* xp = x + ((size_t)b * Cc + c0 + r) * Nn + n0 + q * 16;
    float* op = out + ((size_t)b * Cc + c0 + r) * Nn + n0 + q * 16;
#pragma unroll
    for (int j = 0; j < 4; j++) {
        float4 xv = *(const float4*)(xp + j * 4);
        float4 o4;
        o4.x = tile[q * 16 + j * 4 + 0][r] + xv.x;
        o4.y = tile[q * 16 + j * 4 + 1][r] + xv.y;
        o4.z = tile[q * 16 + j * 4 + 2][r] + xv.z;
        o4.w = tile[q * 16 + j * 4 + 3][r] + xv.w;
        *(float4*)(op + j * 4) = o4;
    }
}

extern "C" void kernel_launch(void* const* d_in, const int* in_sizes, int n_in,
                              void* d_out, int out_size, void* d_ws, size_t ws_size,
                              hipStream_t stream) {
    (void)in_sizes; (void)n_in; (void)out_size; (void)ws_size;
    const float* x     = (const float*)d_in[0];
    const float* Wq    = (const float*)d_in[1];
    const float* bq    = (const float*)d_in[2];
    const float* Wk    = (const float*)d_in[3];
    const float* bk    = (const float*)d_in[4];
    const float* Wv    = (const float*)d_in[5];
    const float* bv    = (const float*)d_in[6];
    const float* gamma = (const float*)d_in[7];
    float* out = (float*)d_out;

    const size_t XTN = (size_t)Bb * Nn * Cc;  // 4,194,304 elements
    unsigned short* xT  = (unsigned short*)d_ws;
    unsigned short* Wbf = xT + XTN;
    unsigned short* qT  = Wbf + 3 * Cc * Cc;
    unsigned short* kT  = qT + XTN;
    unsigned short* vv  = kT + XTN;
    float*          OPT = (float*)(vv + XTN);        // 2 * XTN fp32 = 32MB
    float*          lp  = OPT + 2 * XTN;             // 2*B*N fp32

    hipLaunchKernelGGL(prep_w, dim3(96), dim3(256), 0, stream, Wq, Wk, Wv, Wbf);
    hipLaunchKernelGGL(transpose_x, dim3(Nn / 64, Cc / 64, Bb), dim3(256), 0, stream, x, xT);
    hipLaunchKernelGGL(proj, dim3(Nn / 64, 3, Bb), dim3(256), 0, stream,
                       xT, Wbf, bq, bk, bv, qT, kT, vv);
    hipLaunchKernelGGL(attn, dim3(512), dim3(512), 0, stream,
                       qT, kT, vv, OPT, lp);
    hipLaunchKernelGGL(merge, dim3(Nn / 64, Cc / 64, Bb), dim3(256), 0, stream,
                       OPT, lp, x, gamma, out);
}

// Round 9
// 292.157 us; speedup vs baseline: 1.2856x; 1.2856x over previous
//
#include <hip/hip_runtime.h>
#include <hip/hip_bf16.h>

#define Bb 4
#define Cc 256
#define Nn 4096
#define NV 4160  // V row stride: 4096 + 64 elems (128B) breaks L1 set aliasing

typedef short s16x8 __attribute__((ext_vector_type(8)));
typedef float f32x4 __attribute__((ext_vector_type(4)));

__device__ __forceinline__ unsigned short f2bf(float f) {
    unsigned u = __builtin_bit_cast(unsigned, f);
    u += 0x7FFFu + ((u >> 16) & 1u);
    return (unsigned short)(u >> 16);
}

__device__ __forceinline__ f32x4 mfma16(s16x8 a, s16x8 b, f32x4 c) {
    return __builtin_amdgcn_mfma_f32_16x16x32_bf16(a, b, c, 0, 0, 0);
}

#if __has_builtin(__builtin_amdgcn_global_load_lds)
#define GL16(g, sdst)                                                              \
    __builtin_amdgcn_global_load_lds(                                              \
        (const __attribute__((address_space(1))) unsigned int*)(g),                \
        (__attribute__((address_space(3))) unsigned int*)(sdst), 16, 0, 0)
#else
#define GL16(g, sdst)                                                              \
    do {                                                                           \
        *(s16x8*)((char*)(sdst) + (threadIdx.x & 63) * 16) = *(const s16x8*)(g);   \
    } while (0)
#endif

// ---------------- prep: W fp32 -> bf16 ----------------
__global__ void prep_w(const float* __restrict__ Wq, const float* __restrict__ Wk,
                       const float* __restrict__ Wv, unsigned short* __restrict__ Wbf) {
    int idx = (blockIdx.x * 256 + threadIdx.x) * 8;  // < 3*65536
    int mat = idx >> 16;
    int off = idx & 65535;
    const float* src = (mat == 0) ? Wq : ((mat == 1) ? Wk : Wv);
    float4 a = *(const float4*)(src + off);
    float4 b = *(const float4*)(src + off + 4);
    s16x8 o;
    o[0] = (short)f2bf(a.x); o[1] = (short)f2bf(a.y);
    o[2] = (short)f2bf(a.z); o[3] = (short)f2bf(a.w);
    o[4] = (short)f2bf(b.x); o[5] = (short)f2bf(b.y);
    o[6] = (short)f2bf(b.z); o[7] = (short)f2bf(b.w);
    *(s16x8*)(Wbf + idx) = o;
}

// ---------------- transpose: x[b][c][n] fp32 -> xT[b][n][c] bf16 ----------------
__global__ void transpose_x(const float* __restrict__ x, unsigned short* __restrict__ xT) {
    int b = blockIdx.z, c0 = blockIdx.y * 64, n0 = blockIdx.x * 64;
    __shared__ float tile[64][65];
    int t = threadIdx.x;
    int r = t >> 2, q = t & 3;
    const float* src = x + ((size_t)(b * Cc + c0 + r)) * Nn + n0 + q * 16;
#pragma unroll
    for (int j = 0; j < 4; j++) {
        float4 v4 = *(const float4*)(src + j * 4);
        tile[r][q * 16 + j * 4 + 0] = v4.x;
        tile[r][q * 16 + j * 4 + 1] = v4.y;
        tile[r][q * 16 + j * 4 + 2] = v4.z;
        tile[r][q * 16 + j * 4 + 3] = v4.w;
    }
    __syncthreads();
    unsigned short* dst = xT + ((size_t)b * Nn + n0 + r) * Cc + c0 + q * 16;
    s16x8 o0, o1;
#pragma unroll
    for (int j = 0; j < 8; j++) o0[j] = (short)f2bf(tile[q * 16 + j][r]);
#pragma unroll
    for (int j = 0; j < 8; j++) o1[j] = (short)f2bf(tile[q * 16 + 8 + j][r]);
    *(s16x8*)dst = o0;
    *(s16x8*)(dst + 8) = o1;
}

// ---------------- projections ----------------
__global__ void proj(const unsigned short* __restrict__ xT, const unsigned short* __restrict__ Wbf,
                     const float* __restrict__ bq, const float* __restrict__ bk,
                     const float* __restrict__ bv,
                     unsigned short* __restrict__ qT, unsigned short* __restrict__ kT,
                     unsigned short* __restrict__ vO) {
    int nt0 = blockIdx.x * 64;
    int mat = blockIdx.y;
    int b   = blockIdx.z;
    int t = threadIdx.x, w = t >> 6, l = t & 63;
    int lr = l & 15, lg = l >> 4;
    const unsigned short* Wm  = Wbf + mat * (Cc * Cc);
    const float* bias = (mat == 0) ? bq : ((mat == 1) ? bk : bv);
    const unsigned short* xTb = xT + (size_t)b * Nn * Cc;

    if (mat < 2) {
        unsigned short* out = ((mat == 0) ? qT : kT) + (size_t)b * Nn * Cc;
        int nrow = nt0 + w * 16;
        s16x8 af[8];
#pragma unroll
        for (int kk = 0; kk < 8; kk++)
            af[kk] = *(const s16x8*)(xTb + (nrow + lr) * Cc + kk * 32 + lg * 8);
        for (int ct = 0; ct < 16; ct++) {
            f32x4 acca = {0, 0, 0, 0}, accb = {0, 0, 0, 0};
#pragma unroll
            for (int kk = 0; kk < 8; kk += 2) {
                s16x8 bfa = *(const s16x8*)(Wm + (ct * 16 + lr) * Cc + kk * 32 + lg * 8);
                s16x8 bfb = *(const s16x8*)(Wm + (ct * 16 + lr) * Cc + (kk + 1) * 32 + lg * 8);
                acca = mfma16(af[kk], bfa, acca);
                accb = mfma16(af[kk + 1], bfb, accb);
            }
            f32x4 acc = acca + accb;
            float bb = bias[ct * 16 + lr];
#pragma unroll
            for (int r = 0; r < 4; r++)
                out[(nrow + lg * 4 + r) * Cc + ct * 16 + lr] = f2bf(acc[r] + bb);
        }
    } else {
        unsigned short* out = vO + (size_t)b * Cc * NV;
        for (int mt = 0; mt < 4; mt++) {
            int crow = (w * 4 + mt) * 16;
            s16x8 af[8];
#pragma unroll
            for (int kk = 0; kk < 8; kk++)
                af[kk] = *(const s16x8*)(Wm + (crow + lr) * Cc + kk * 32 + lg * 8);
#pragma unroll
            for (int nt = 0; nt < 4; nt++) {
                f32x4 acca = {0, 0, 0, 0}, accb = {0, 0, 0, 0};
#pragma unroll
                for (int kk = 0; kk < 8; kk += 2) {
                    s16x8 bfa = *(const s16x8*)(xTb + (nt0 + nt * 16 + lr) * Cc + kk * 32 + lg * 8);
                    s16x8 bfb = *(const s16x8*)(xTb + (nt0 + nt * 16 + lr) * Cc + (kk + 1) * 32 + lg * 8);
                    acca = mfma16(af[kk], bfa, acca);
                    accb = mfma16(af[kk + 1], bfb, accb);
                }
                f32x4 acc = acca + accb;
#pragma unroll
                for (int r = 0; r < 4; r++) {
                    float bb = bias[crow + lg * 4 + r];
                    out[(size_t)(crow + lg * 4 + r) * NV + nt0 + nt * 16 + lr] = f2bf(acc[r] + bb);
                }
            }
        }
    }
}

// ---------------- fused flash attention ----------------
// R5 structure verbatim (233us baseline): 256 blocks, id&7=(b,s) combo ->
// one combo per XCD (1MB K + 1MB V slice L2-resident, 32 lockstep blocks,
// 16MB total fetch). Each wave: 32 i-rows as two 16-row halves sharing every
// K/V fragment. K tile LDS dbuf (global_load_lds + (row&7)<<4 XOR swizzle).
// V direct global->reg — NOW with NV=4160 padded row stride so each
// V-fragment's 16 rows hit 16 DIFFERENT L1 sets (was: all same set, 4-way
// thrash, every access at L2 latency — the cross-round ~9k cyc/tile invariant).
__global__ void __launch_bounds__(256, 1)
attn(const unsigned short* __restrict__ qT, const unsigned short* __restrict__ kT,
     const unsigned short* __restrict__ vv,
     float* __restrict__ OPT, float* __restrict__ lp) {
    int id = blockIdx.x;
    int bs = id & 7, b = bs >> 1, s = bs & 1, iblk = id >> 3;
    int t = threadIdx.x, w = t >> 6, l = t & 63;
    int lr = l & 15, lg = l >> 4;
    int i0 = iblk * 128 + w * 32;

    __shared__ char Ks[2][16384];                // K tile dbuf: 32 rows x 512B
    __shared__ unsigned short P_lds[4][2][512];  // per-wave, per-half [16][32]
    unsigned short* plA = P_lds[w][0];
    unsigned short* plB = P_lds[w][1];

    const unsigned short* qb = qT + ((size_t)b * Nn + i0) * Cc;
    const char* kbase = (const char*)(kT + ((size_t)b * Nn + s * 2048) * Cc);
    const unsigned short* vbase = vv + (size_t)b * Cc * NV + s * 2048;

    s16x8 qfA[8], qfB[8];
#pragma unroll
    for (int kk = 0; kk < 8; kk++) {
        qfA[kk] = *(const s16x8*)(qb + lr * Cc + kk * 32 + lg * 8);
        qfB[kk] = *(const s16x8*)(qb + (16 + lr) * Cc + kk * 32 + lg * 8);
    }

    f32x4 OA[16], OB[16];
#pragma unroll
    for (int ct = 0; ct < 16; ct++) { OA[ct] = {0, 0, 0, 0}; OB[ct] = {0, 0, 0, 0}; }
    float lsA[4] = {0, 0, 0, 0}, lsB[4] = {0, 0, 0, 0};
    const float L2E = 1.44269504088896340736f;

// stage 16KB K tile (32 rows x 512B) into Ks[bufi]; wave w covers chunks w*4..w*4+3
#define STAGEK(bufi, jt)                                                        \
    {                                                                           \
        const char* ksl_ = kbase + (size_t)(jt) * 16384;                        \
        _Pragma("unroll") for (int i_ = 0; i_ < 4; i_++) {                      \
            int chunk_ = w * 4 + i_;                                            \
            int L_ = chunk_ * 1024 + l * 16;                                    \
            int row_ = L_ >> 9;                                                 \
            GL16(ksl_ + (L_ ^ ((row_ & 7) << 4)), &Ks[bufi][chunk_ * 1024]);    \
        }                                                                       \
    }

    STAGEK(0, 0);
    asm volatile("s_waitcnt vmcnt(0)" ::: "memory");
    __syncthreads();
    int buf = 0;

    for (int jt = 0; jt < 64; jt++) {
        int j0 = jt * 32;
        // ---- V loads first: consumed at PV (latency covered by QK+softmax) ----
        s16x8 vf[16];
#pragma unroll
        for (int ct = 0; ct < 16; ct++)
            vf[ct] = *(const s16x8*)(vbase + (size_t)(ct * 16 + lr) * NV + j0 + lg * 8);
        // ---- prefetch next K tile into other buffer ----
        if (jt < 63) STAGEK(buf ^ 1, jt + 1);
        // ---- QK^T from K-LDS: each k-frag feeds BOTH halves ----
        const char* ksb = Ks[buf];
        f32x4 EA0 = {0, 0, 0, 0}, EA1 = {0, 0, 0, 0};
        f32x4 EB0 = {0, 0, 0, 0}, EB1 = {0, 0, 0, 0};
#pragma unroll
        for (int kk = 0; kk < 8; kk++) {
            int cb = (kk * 64 + lg * 16) ^ ((lr & 7) << 4);
            s16x8 k0 = *(const s16x8*)(ksb + lr * 512 + cb);
            s16x8 k1 = *(const s16x8*)(ksb + (16 + lr) * 512 + cb);
            EA0 = mfma16(qfA[kk], k0, EA0);
            EA1 = mfma16(qfA[kk], k1, EA1);
            EB0 = mfma16(qfB[kk], k0, EB0);
            EB1 = mfma16(qfB[kk], k1, EB1);
        }
        // ---- shift-free softmax, both halves ----
        float pA0[4], pA1[4], pB0[4], pB1[4];
#pragma unroll
        for (int r = 0; r < 4; r++) {
            pA0[r] = exp2f(EA0[r] * L2E);
            pA1[r] = exp2f(EA1[r] * L2E);
            pB0[r] = exp2f(EB0[r] * L2E);
            pB1[r] = exp2f(EB1[r] * L2E);
            lsA[r] += pA0[r] + pA1[r];
            lsB[r] += pB0[r] + pB1[r];
        }
        // ---- P -> bf16 -> LDS roundtrip (wave-synchronous, proven layout) ----
#pragma unroll
        for (int r = 0; r < 4; r++) {
            plA[(lg * 4 + r) * 32 + lr] = f2bf(pA0[r]);
            plA[(lg * 4 + r) * 32 + 16 + lr] = f2bf(pA1[r]);
            plB[(lg * 4 + r) * 32 + lr] = f2bf(pB0[r]);
            plB[(lg * 4 + r) * 32 + 16 + lr] = f2bf(pB1[r]);
        }
        asm volatile("s_waitcnt lgkmcnt(0)" ::: "memory");
        __builtin_amdgcn_sched_barrier(0);
        s16x8 pfA = *(const s16x8*)(plA + lr * 32 + lg * 8);
        s16x8 pfB = *(const s16x8*)(plB + lr * 32 + lg * 8);
        // ---- PV: each v-frag feeds both halves ----
#pragma unroll
        for (int ct = 0; ct < 16; ct++) {
            OA[ct] = mfma16(pfA, vf[ct], OA[ct]);
            OB[ct] = mfma16(pfB, vf[ct], OB[ct]);
        }
        asm volatile("s_waitcnt vmcnt(0)" ::: "memory");
        __syncthreads();
        buf ^= 1;
    }

    // ---- l reduction across 16 lanes of each row group ----
#pragma unroll
    for (int r = 0; r < 4; r++) {
#pragma unroll
        for (int msk = 1; msk <= 8; msk <<= 1) {
            lsA[r] += __shfl_xor(lsA[r], msk);
            lsB[r] += __shfl_xor(lsB[r], msk);
        }
    }
    size_t sb = (size_t)(s * Bb + b);
    if (lr == 0) {
#pragma unroll
        for (int r = 0; r < 4; r++) {
            lp[sb * Nn + i0 + lg * 4 + r] = lsA[r];
            lp[sb * Nn + i0 + 16 + lg * 4 + r] = lsB[r];
        }
    }
    // ---- fp32 partials, [n][c] layout ----
    float* ob = OPT + sb * Nn * Cc;
#pragma unroll
    for (int ct = 0; ct < 16; ct++) {
#pragma unroll
        for (int r = 0; r < 4; r++) {
            ob[(size_t)(i0 + lg * 4 + r) * Cc + ct * 16 + lr] = OA[ct][r];
            ob[(size_t)(i0 + 16 + lg * 4 + r) * Cc + ct * 16 + lr] = OB[ct][r];
        }
    }
#undef STAGEK
}

// ---------------- merge partials + transpose + epilogue ----------------
// out[b][c][n] = gamma * (OPT0+OPT1)[n][c] / (l0+l1)[n] + x[b][c][n]
__global__ void __launch_bounds__(256)
merge(const float* __restrict__ OPT, const float* __restrict__ lp,
      const float* __restrict__ x, const float* __restrict__ gamma,
      float* __restrict__ out) {
    int b = blockIdx.z, c0 = blockIdx.y * 64, n0 = blockIdx.x * 64;
    __shared__ float tile[64][65];
    __shared__ float linv[64];
    int t = threadIdx.x;
    if (t < 64) {
        float sum = lp[(size_t)b * Nn + n0 + t] + lp[(size_t)(Bb + b) * Nn + n0 + t];
        linv[t] = 1.0f / sum;
    }
    __syncthreads();
    float g = gamma[0];
    int r = t >> 2, q = t & 3;
    const float* p0 = OPT + ((size_t)b * Nn + n0 + r) * Cc + c0 + q * 16;
    const float* p1 = OPT + ((size_t)(Bb + b) * Nn + n0 + r) * Cc + c0 + q * 16;
    float sc = g * linv[r];
#pragma unroll
    for (int j = 0; j < 4; j++) {
        float4 a0 = *(const float4*)(p0 + j * 4);
        float4 a1 = *(const float4*)(p1 + j * 4);
        tile[r][q * 16 + j * 4 + 0] = sc * (a0.x + a1.x);
        tile[r][q * 16 + j * 4 + 1] = sc * (a0.y + a1.y);
        tile[r][q * 16 + j * 4 + 2] = sc * (a0.z + a1.z);
        tile[r][q * 16 + j * 4 + 3] = sc * (a0.w + a1.w);
    }
    __syncthreads();
    const float* xp = x + ((size_t)b * Cc + c0 + r) * Nn + n0 + q * 16;
    float* op = out + ((size_t)b * Cc + c0 + r) * Nn + n0 + q * 16;
#pragma unroll
    for (int j = 0; j < 4; j++) {
        float4 xv = *(const float4*)(xp + j * 4);
        float4 o4;
        o4.x = tile[q * 16 + j * 4 + 0][r] + xv.x;
        o4.y = tile[q * 16 + j * 4 + 1][r] + xv.y;
        o4.z = tile[q * 16 + j * 4 + 2][r] + xv.z;
        o4.w = tile[q * 16 + j * 4 + 3][r] + xv.w;
        *(float4*)(op + j * 4) = o4;
    }
}

extern "C" void kernel_launch(void* const* d_in, const int* in_sizes, int n_in,
                              void* d_out, int out_size, void* d_ws, size_t ws_size,
                              hipStream_t stream) {
    (void)in_sizes; (void)n_in; (void)out_size; (void)ws_size;
    const float* x     = (const float*)d_in[0];
    const float* Wq    = (const float*)d_in[1];
    const float* bq    = (const float*)d_in[2];
    const float* Wk    = (const float*)d_in[3];
    const float* bk    = (const float*)d_in[4];
    const float* Wv    = (const float*)d_in[5];
    const float* bv    = (const float*)d_in[6];
    const float* gamma = (const float*)d_in[7];
    float* out = (float*)d_out;

    const size_t XTN = (size_t)Bb * Nn * Cc;   // 4,194,304 elements
    const size_t VSZ = (size_t)Bb * Cc * NV;   // padded V: 4,259,840 elements
    unsigned short* xT  = (unsigned short*)d_ws;
    unsigned short* Wbf = xT + XTN;
    unsigned short* qT  = Wbf + 3 * Cc * Cc;
    unsigned short* kT  = qT + XTN;
    unsigned short* vv  = kT + XTN;
    float*          OPT = (float*)(vv + VSZ);        // 2 * XTN fp32 = 32MB
    float*          lp  = OPT + 2 * XTN;             // 2*B*N fp32

    hipLaunchKernelGGL(prep_w, dim3(96), dim3(256), 0, stream, Wq, Wk, Wv, Wbf);
    hipLaunchKernelGGL(transpose_x, dim3(Nn / 64, Cc / 64, Bb), dim3(256), 0, stream, x, xT);
    hipLaunchKernelGGL(proj, dim3(Nn / 64, 3, Bb), dim3(256), 0, stream,
                       xT, Wbf, bq, bk, bv, qT, kT, vv);
    hipLaunchKernelGGL(attn, dim3(256), dim3(256), 0, stream,
                       qT, kT, vv, OPT, lp);
    hipLaunchKernelGGL(merge, dim3(Nn / 64, Cc / 64, Bb), dim3(256), 0, stream,
                       OPT, lp, x, gamma, out);
}

// Round 10
// 202.251 us; speedup vs baseline: 1.8571x; 1.4445x over previous
//
#include <hip/hip_runtime.h>
#include <hip/hip_bf16.h>

#define Bb 4
#define Cc 256
#define Nn 4096
#define NV 4160  // V row stride (kept from R9; addresses computed explicitly)

typedef short s16x8 __attribute__((ext_vector_type(8)));
typedef float f32x4 __attribute__((ext_vector_type(4)));

__device__ __forceinline__ unsigned short f2bf(float f) {
    unsigned u = __builtin_bit_cast(unsigned, f);
    u += 0x7FFFu + ((u >> 16) & 1u);
    return (unsigned short)(u >> 16);
}

__device__ __forceinline__ f32x4 mfma16(s16x8 a, s16x8 b, f32x4 c) {
    return __builtin_amdgcn_mfma_f32_16x16x32_bf16(a, b, c, 0, 0, 0);
}

#if __has_builtin(__builtin_amdgcn_global_load_lds)
#define GL16(g, sdst)                                                              \
    __builtin_amdgcn_global_load_lds(                                              \
        (const __attribute__((address_space(1))) unsigned int*)(g),                \
        (__attribute__((address_space(3))) unsigned int*)(sdst), 16, 0, 0)
#else
#define GL16(g, sdst)                                                              \
    do {                                                                           \
        *(s16x8*)((char*)(sdst) + (threadIdx.x & 63) * 16) = *(const s16x8*)(g);   \
    } while (0)
#endif

// ---------------- prep: W fp32 -> bf16 ----------------
__global__ void prep_w(const float* __restrict__ Wq, const float* __restrict__ Wk,
                       const float* __restrict__ Wv, unsigned short* __restrict__ Wbf) {
    int idx = (blockIdx.x * 256 + threadIdx.x) * 8;  // < 3*65536
    int mat = idx >> 16;
    int off = idx & 65535;
    const float* src = (mat == 0) ? Wq : ((mat == 1) ? Wk : Wv);
    float4 a = *(const float4*)(src + off);
    float4 b = *(const float4*)(src + off + 4);
    s16x8 o;
    o[0] = (short)f2bf(a.x); o[1] = (short)f2bf(a.y);
    o[2] = (short)f2bf(a.z); o[3] = (short)f2bf(a.w);
    o[4] = (short)f2bf(b.x); o[5] = (short)f2bf(b.y);
    o[6] = (short)f2bf(b.z); o[7] = (short)f2bf(b.w);
    *(s16x8*)(Wbf + idx) = o;
}

// ---------------- transpose: x[b][c][n] fp32 -> xT[b][n][c] bf16 ----------------
__global__ void transpose_x(const float* __restrict__ x, unsigned short* __restrict__ xT) {
    int b = blockIdx.z, c0 = blockIdx.y * 64, n0 = blockIdx.x * 64;
    __shared__ float tile[64][65];
    int t = threadIdx.x;
    int r = t >> 2, q = t & 3;
    const float* src = x + ((size_t)(b * Cc + c0 + r)) * Nn + n0 + q * 16;
#pragma unroll
    for (int j = 0; j < 4; j++) {
        float4 v4 = *(const float4*)(src + j * 4);
        tile[r][q * 16 + j * 4 + 0] = v4.x;
        tile[r][q * 16 + j * 4 + 1] = v4.y;
        tile[r][q * 16 + j * 4 + 2] = v4.z;
        tile[r][q * 16 + j * 4 + 3] = v4.w;
    }
    __syncthreads();
    unsigned short* dst = xT + ((size_t)b * Nn + n0 + r) * Cc + c0 + q * 16;
    s16x8 o0, o1;
#pragma unroll
    for (int j = 0; j < 8; j++) o0[j] = (short)f2bf(tile[q * 16 + j][r]);
#pragma unroll
    for (int j = 0; j < 8; j++) o1[j] = (short)f2bf(tile[q * 16 + 8 + j][r]);
    *(s16x8*)dst = o0;
    *(s16x8*)(dst + 8) = o1;
}

// ---------------- projections ----------------
__global__ void proj(const unsigned short* __restrict__ xT, const unsigned short* __restrict__ Wbf,
                     const float* __restrict__ bq, const float* __restrict__ bk,
                     const float* __restrict__ bv,
                     unsigned short* __restrict__ qT, unsigned short* __restrict__ kT,
                     unsigned short* __restrict__ vO) {
    int nt0 = blockIdx.x * 64;
    int mat = blockIdx.y;
    int b   = blockIdx.z;
    int t = threadIdx.x, w = t >> 6, l = t & 63;
    int lr = l & 15, lg = l >> 4;
    const unsigned short* Wm  = Wbf + mat * (Cc * Cc);
    const float* bias = (mat == 0) ? bq : ((mat == 1) ? bk : bv);
    const unsigned short* xTb = xT + (size_t)b * Nn * Cc;

    if (mat < 2) {
        unsigned short* out = ((mat == 0) ? qT : kT) + (size_t)b * Nn * Cc;
        int nrow = nt0 + w * 16;
        s16x8 af[8];
#pragma unroll
        for (int kk = 0; kk < 8; kk++)
            af[kk] = *(const s16x8*)(xTb + (nrow + lr) * Cc + kk * 32 + lg * 8);
        for (int ct = 0; ct < 16; ct++) {
            f32x4 acca = {0, 0, 0, 0}, accb = {0, 0, 0, 0};
#pragma unroll
            for (int kk = 0; kk < 8; kk += 2) {
                s16x8 bfa = *(const s16x8*)(Wm + (ct * 16 + lr) * Cc + kk * 32 + lg * 8);
                s16x8 bfb = *(const s16x8*)(Wm + (ct * 16 + lr) * Cc + (kk + 1) * 32 + lg * 8);
                acca = mfma16(af[kk], bfa, acca);
                accb = mfma16(af[kk + 1], bfb, accb);
            }
            f32x4 acc = acca + accb;
            float bb = bias[ct * 16 + lr];
#pragma unroll
            for (int r = 0; r < 4; r++)
                out[(nrow + lg * 4 + r) * Cc + ct * 16 + lr] = f2bf(acc[r] + bb);
        }
    } else {
        unsigned short* out = vO + (size_t)b * Cc * NV;
        for (int mt = 0; mt < 4; mt++) {
            int crow = (w * 4 + mt) * 16;
            s16x8 af[8];
#pragma unroll
            for (int kk = 0; kk < 8; kk++)
                af[kk] = *(const s16x8*)(Wm + (crow + lr) * Cc + kk * 32 + lg * 8);
#pragma unroll
            for (int nt = 0; nt < 4; nt++) {
                f32x4 acca = {0, 0, 0, 0}, accb = {0, 0, 0, 0};
#pragma unroll
                for (int kk = 0; kk < 8; kk += 2) {
                    s16x8 bfa = *(const s16x8*)(xTb + (nt0 + nt * 16 + lr) * Cc + kk * 32 + lg * 8);
                    s16x8 bfb = *(const s16x8*)(xTb + (nt0 + nt * 16 + lr) * Cc + (kk + 1) * 32 + lg * 8);
                    acca = mfma16(af[kk], bfa, acca);
                    accb = mfma16(af[kk + 1], bfb, accb);
                }
                f32x4 acc = acca + accb;
#pragma unroll
                for (int r = 0; r < 4; r++) {
                    float bb = bias[crow + lg * 4 + r];
                    out[(size_t)(crow + lg * 4 + r) * NV + nt0 + nt * 16 + lr] = f2bf(acc[r] + bb);
                }
            }
        }
    }
}

// ---------------- fused flash attention ----------------
// R9 structure with ONE change: V is LDS-staged like K (dbuf global_load_lds)
// instead of per-wave global gathers. Per CU per tile: 32KB DMA (K+V once)
// + LDS reads, replacing ~1k L1/TA line-gather transactions (4 waves x 16
// instr x 16 lines) that was the ~8.7k cyc/tile invariant.
// V tile layout: 256 rows (c) x 64B (32 j bf16); swizzle f(row)=((row>>1)&3)<<4
// applied to SOURCE column bytes at staging and to ds_read addr (rule #21);
// reader lands 2 lanes/bank = free (m136).
__global__ void __launch_bounds__(256, 1)
attn(const unsigned short* __restrict__ qT, const unsigned short* __restrict__ kT,
     const unsigned short* __restrict__ vv,
     float* __restrict__ OPT, float* __restrict__ lp) {
    int id = blockIdx.x;
    int bs = id & 7, b = bs >> 1, s = bs & 1, iblk = id >> 3;
    int t = threadIdx.x, w = t >> 6, l = t & 63;
    int lr = l & 15, lg = l >> 4;
    int i0 = iblk * 128 + w * 32;

    __shared__ char Ks[2][16384];                // K tile dbuf: 32 rows x 512B
    __shared__ char Vs[2][16384];                // V tile dbuf: 256 rows x 64B
    __shared__ unsigned short P_lds[4][2][512];  // per-wave, per-half [16][32]
    unsigned short* plA = P_lds[w][0];
    unsigned short* plB = P_lds[w][1];

    const unsigned short* qb = qT + ((size_t)b * Nn + i0) * Cc;
    const char* kbase = (const char*)(kT + ((size_t)b * Nn + s * 2048) * Cc);
    const char* vbase = (const char*)(vv + (size_t)b * Cc * NV + s * 2048);

    s16x8 qfA[8], qfB[8];
#pragma unroll
    for (int kk = 0; kk < 8; kk++) {
        qfA[kk] = *(const s16x8*)(qb + lr * Cc + kk * 32 + lg * 8);
        qfB[kk] = *(const s16x8*)(qb + (16 + lr) * Cc + kk * 32 + lg * 8);
    }

    f32x4 OA[16], OB[16];
#pragma unroll
    for (int ct = 0; ct < 16; ct++) { OA[ct] = {0, 0, 0, 0}; OB[ct] = {0, 0, 0, 0}; }
    float lsA[4] = {0, 0, 0, 0}, lsB[4] = {0, 0, 0, 0};
    const float L2E = 1.44269504088896340736f;

// stage 16KB K tile (32 rows x 512B) into Ks[bufi]; wave w covers chunks w*4..w*4+3
#define STAGEK(bufi, jt)                                                        \
    {                                                                           \
        const char* ksl_ = kbase + (size_t)(jt) * 16384;                        \
        _Pragma("unroll") for (int i_ = 0; i_ < 4; i_++) {                      \
            int chunk_ = w * 4 + i_;                                            \
            int L_ = chunk_ * 1024 + l * 16;                                    \
            int row_ = L_ >> 9;                                                 \
            GL16(ksl_ + (L_ ^ ((row_ & 7) << 4)), &Ks[bufi][chunk_ * 1024]);    \
        }                                                                       \
    }

// stage 16KB V tile (256 rows x 64B) into Vs[bufi]; lane l covers row ch*16+(l>>2)
// source col-bytes pre-swizzled by ((row>>1)&3)<<4 = ((l>>3)&3)<<4 per lane
#define STAGEV(bufi, jt)                                                        \
    {                                                                           \
        _Pragma("unroll") for (int i_ = 0; i_ < 4; i_++) {                      \
            int chunk_ = w * 4 + i_;                                            \
            int row_ = chunk_ * 16 + (l >> 2);                                  \
            int colb_ = ((l & 3) * 16) ^ (((l >> 3) & 3) << 4);                 \
            GL16(vbase + (size_t)row_ * (NV * 2) + (size_t)(jt) * 64 + colb_,   \
                 &Vs[bufi][chunk_ * 1024]);                                     \
        }                                                                       \
    }

    STAGEK(0, 0);
    STAGEV(0, 0);
    asm volatile("s_waitcnt vmcnt(0)" ::: "memory");
    __syncthreads();
    int buf = 0;

    for (int jt = 0; jt < 64; jt++) {
        // ---- prefetch next K+V tiles into other buffer ----
        if (jt < 63) {
            STAGEK(buf ^ 1, jt + 1);
            STAGEV(buf ^ 1, jt + 1);
        }
        // ---- QK^T from K-LDS: each k-frag feeds BOTH halves ----
        const char* ksb = Ks[buf];
        f32x4 EA0 = {0, 0, 0, 0}, EA1 = {0, 0, 0, 0};
        f32x4 EB0 = {0, 0, 0, 0}, EB1 = {0, 0, 0, 0};
#pragma unroll
        for (int kk = 0; kk < 8; kk++) {
            int cb = (kk * 64 + lg * 16) ^ ((lr & 7) << 4);
            s16x8 k0 = *(const s16x8*)(ksb + lr * 512 + cb);
            s16x8 k1 = *(const s16x8*)(ksb + (16 + lr) * 512 + cb);
            EA0 = mfma16(qfA[kk], k0, EA0);
            EA1 = mfma16(qfA[kk], k1, EA1);
            EB0 = mfma16(qfB[kk], k0, EB0);
            EB1 = mfma16(qfB[kk], k1, EB1);
        }
        // ---- shift-free softmax, both halves ----
        float pA0[4], pA1[4], pB0[4], pB1[4];
#pragma unroll
        for (int r = 0; r < 4; r++) {
            pA0[r] = exp2f(EA0[r] * L2E);
            pA1[r] = exp2f(EA1[r] * L2E);
            pB0[r] = exp2f(EB0[r] * L2E);
            pB1[r] = exp2f(EB1[r] * L2E);
            lsA[r] += pA0[r] + pA1[r];
            lsB[r] += pB0[r] + pB1[r];
        }
        // ---- P -> bf16 -> LDS roundtrip (wave-synchronous, proven layout) ----
#pragma unroll
        for (int r = 0; r < 4; r++) {
            plA[(lg * 4 + r) * 32 + lr] = f2bf(pA0[r]);
            plA[(lg * 4 + r) * 32 + 16 + lr] = f2bf(pA1[r]);
            plB[(lg * 4 + r) * 32 + lr] = f2bf(pB0[r]);
            plB[(lg * 4 + r) * 32 + 16 + lr] = f2bf(pB1[r]);
        }
        asm volatile("s_waitcnt lgkmcnt(0)" ::: "memory");
        __builtin_amdgcn_sched_barrier(0);
        s16x8 pfA = *(const s16x8*)(plA + lr * 32 + lg * 8);
        s16x8 pfB = *(const s16x8*)(plB + lr * 32 + lg * 8);
        // ---- PV: V fragments from LDS (swizzled; 2 lanes/bank = free) ----
        const char* vsb = Vs[buf];
        int vswz = (lg * 16) ^ (((lr >> 1) & 3) << 4);
#pragma unroll
        for (int ct = 0; ct < 16; ct++) {
            s16x8 vf = *(const s16x8*)(vsb + (ct * 16 + lr) * 64 + vswz);
            OA[ct] = mfma16(pfA, vf, OA[ct]);
            OB[ct] = mfma16(pfB, vf, OB[ct]);
        }
        asm volatile("s_waitcnt vmcnt(0)" ::: "memory");
        __syncthreads();
        buf ^= 1;
    }

    // ---- l reduction across 16 lanes of each row group ----
#pragma unroll
    for (int r = 0; r < 4; r++) {
#pragma unroll
        for (int msk = 1; msk <= 8; msk <<= 1) {
            lsA[r] += __shfl_xor(lsA[r], msk);
            lsB[r] += __shfl_xor(lsB[r], msk);
        }
    }
    size_t sb = (size_t)(s * Bb + b);
    if (lr == 0) {
#pragma unroll
        for (int r = 0; r < 4; r++) {
            lp[sb * Nn + i0 + lg * 4 + r] = lsA[r];
            lp[sb * Nn + i0 + 16 + lg * 4 + r] = lsB[r];
        }
    }
    // ---- fp32 partials, [n][c] layout ----
    float* ob = OPT + sb * Nn * Cc;
#pragma unroll
    for (int ct = 0; ct < 16; ct++) {
#pragma unroll
        for (int r = 0; r < 4; r++) {
            ob[(size_t)(i0 + lg * 4 + r) * Cc + ct * 16 + lr] = OA[ct][r];
            ob[(size_t)(i0 + 16 + lg * 4 + r) * Cc + ct * 16 + lr] = OB[ct][r];
        }
    }
#undef STAGEK
#undef STAGEV
}

// ---------------- merge partials + transpose + epilogue ----------------
// out[b][c][n] = gamma * (OPT0+OPT1)[n][c] / (l0+l1)[n] + x[b][c][n]
__global__ void __launch_bounds__(256)
merge(const float* __restrict__ OPT, const float* __restrict__ lp,
      const float* __restrict__ x, const float* __restrict__ gamma,
      float* __restrict__ out) {
    int b = blockIdx.z, c0 = blockIdx.y * 64, n0 = blockIdx.x * 64;
    __shared__ float tile[64][65];
    __shared__ float linv[64];
    int t = threadIdx.x;
    if (t < 64) {
        float sum = lp[(size_t)b * Nn + n0 + t] + lp[(size_t)(Bb + b) * Nn + n0 + t];
        linv[t] = 1.0f / sum;
    }
    __syncthreads();
    float g = gamma[0];
    int r = t >> 2, q = t & 3;
    const float* p0 = OPT + ((size_t)b * Nn + n0 + r) * Cc + c0 + q * 16;
    const float* p1 = OPT + ((size_t)(Bb + b) * Nn + n0 + r) * Cc + c0 + q * 16;
    float sc = g * linv[r];
#pragma unroll
    for (int j = 0; j < 4; j++) {
        float4 a0 = *(const float4*)(p0 + j * 4);
        float4 a1 = *(const float4*)(p1 + j * 4);
        tile[r][q * 16 + j * 4 + 0] = sc * (a0.x + a1.x);
        tile[r][q * 16 + j * 4 + 1] = sc * (a0.y + a1.y);
        tile[r][q * 16 + j * 4 + 2] = sc * (a0.z + a1.z);
        tile[r][q * 16 + j * 4 + 3] = sc * (a0.w + a1.w);
    }
    __syncthreads();
    const float* xp = x + ((size_t)b * Cc + c0 + r) * Nn + n0 + q * 16;
    float* op = out + ((size_t)b * Cc + c0 + r) * Nn + n0 + q * 16;
#pragma unroll
    for (int j = 0; j < 4; j++) {
        float4 xv = *(const float4*)(xp + j * 4);
        float4 o4;
        o4.x = tile[q * 16 + j * 4 + 0][r] + xv.x;
        o4.y = tile[q * 16 + j * 4 + 1][r] + xv.y;
        o4.z = tile[q * 16 + j * 4 + 2][r] + xv.z;
        o4.w = tile[q * 16 + j * 4 + 3][r] + xv.w;
        *(float4*)(op + j * 4) = o4;
    }
}

extern "C" void kernel_launch(void* const* d_in, const int* in_sizes, int n_in,
                              void* d_out, int out_size, void* d_ws, size_t ws_size,
                              hipStream_t stream) {
    (void)in_sizes; (void)n_in; (void)out_size; (void)ws_size;
    const float* x     = (const float*)d_in[0];
    const float* Wq    = (const float*)d_in[1];
    const float* bq    = (const float*)d_in[2];
    const float* Wk    = (const float*)d_in[3];
    const float* bk    = (const float*)d_in[4];
    const float* Wv    = (const float*)d_in[5];
    const float* bv    = (const float*)d_in[6];
    const float* gamma = (const float*)d_in[7];
    float* out = (float*)d_out;

    const size_t XTN = (size_t)Bb * Nn * Cc;   // 4,194,304 elements
    const size_t VSZ = (size_t)Bb * Cc * NV;   // padded V
    unsigned short* xT  = (unsigned short*)d_ws;
    unsigned short* Wbf = xT + XTN;
    unsigned short* qT  = Wbf + 3 * Cc * Cc;
    unsigned short* kT  = qT + XTN;
    unsigned short* vv  = kT + XTN;
    float*          OPT = (float*)(vv + VSZ);        // 2 * XTN fp32 = 32MB
    float*          lp  = OPT + 2 * XTN;             // 2*B*N fp32

    hipLaunchKernelGGL(prep_w, dim3(96), dim3(256), 0, stream, Wq, Wk, Wv, Wbf);
    hipLaunchKernelGGL(transpose_x, dim3(Nn / 64, Cc / 64, Bb), dim3(256), 0, stream, x, xT);
    hipLaunchKernelGGL(proj, dim3(Nn / 64, 3, Bb), dim3(256), 0, stream,
                       xT, Wbf, bq, bk, bv, qT, kT, vv);
    hipLaunchKernelGGL(attn, dim3(256), dim3(256), 0, stream,
                       qT, kT, vv, OPT, lp);
    hipLaunchKernelGGL(merge, dim3(Nn / 64, Cc / 64, Bb), dim3(256), 0, stream,
                       OPT, lp, x, gamma, out);
}

// Round 11
// 180.086 us; speedup vs baseline: 2.0857x; 1.1231x over previous
//
#include <hip/hip_runtime.h>
#include <hip/hip_bf16.h>

#define Bb 4
#define Cc 256
#define Nn 4096
#define NV 4160  // V row stride (padded; addresses computed explicitly)

typedef short s16x8 __attribute__((ext_vector_type(8)));
typedef float f32x4 __attribute__((ext_vector_type(4)));

__device__ __forceinline__ unsigned short f2bf(float f) {
    unsigned u = __builtin_bit_cast(unsigned, f);
    u += 0x7FFFu + ((u >> 16) & 1u);
    return (unsigned short)(u >> 16);
}

__device__ __forceinline__ f32x4 mfma16(s16x8 a, s16x8 b, f32x4 c) {
    return __builtin_amdgcn_mfma_f32_16x16x32_bf16(a, b, c, 0, 0, 0);
}

#if __has_builtin(__builtin_amdgcn_global_load_lds)
#define GL16(g, sdst)                                                              \
    __builtin_amdgcn_global_load_lds(                                              \
        (const __attribute__((address_space(1))) unsigned int*)(g),                \
        (__attribute__((address_space(3))) unsigned int*)(sdst), 16, 0, 0)
#else
#define GL16(g, sdst)                                                              \
    do {                                                                           \
        *(s16x8*)((char*)(sdst) + (threadIdx.x & 63) * 16) = *(const s16x8*)(g);   \
    } while (0)
#endif

// ---------------- prep: W fp32 -> bf16 ----------------
__global__ void prep_w(const float* __restrict__ Wq, const float* __restrict__ Wk,
                       const float* __restrict__ Wv, unsigned short* __restrict__ Wbf) {
    int idx = (blockIdx.x * 256 + threadIdx.x) * 8;  // < 3*65536
    int mat = idx >> 16;
    int off = idx & 65535;
    const float* src = (mat == 0) ? Wq : ((mat == 1) ? Wk : Wv);
    float4 a = *(const float4*)(src + off);
    float4 b = *(const float4*)(src + off + 4);
    s16x8 o;
    o[0] = (short)f2bf(a.x); o[1] = (short)f2bf(a.y);
    o[2] = (short)f2bf(a.z); o[3] = (short)f2bf(a.w);
    o[4] = (short)f2bf(b.x); o[5] = (short)f2bf(b.y);
    o[6] = (short)f2bf(b.z); o[7] = (short)f2bf(b.w);
    *(s16x8*)(Wbf + idx) = o;
}

// ---------------- transpose: x[b][c][n] fp32 -> xT[b][n][c] bf16 ----------------
__global__ void transpose_x(const float* __restrict__ x, unsigned short* __restrict__ xT) {
    int b = blockIdx.z, c0 = blockIdx.y * 64, n0 = blockIdx.x * 64;
    __shared__ float tile[64][65];
    int t = threadIdx.x;
    int r = t >> 2, q = t & 3;
    const float* src = x + ((size_t)(b * Cc + c0 + r)) * Nn + n0 + q * 16;
#pragma unroll
    for (int j = 0; j < 4; j++) {
        float4 v4 = *(const float4*)(src + j * 4);
        tile[r][q * 16 + j * 4 + 0] = v4.x;
        tile[r][q * 16 + j * 4 + 1] = v4.y;
        tile[r][q * 16 + j * 4 + 2] = v4.z;
        tile[r][q * 16 + j * 4 + 3] = v4.w;
    }
    __syncthreads();
    unsigned short* dst = xT + ((size_t)b * Nn + n0 + r) * Cc + c0 + q * 16;
    s16x8 o0, o1;
#pragma unroll
    for (int j = 0; j < 8; j++) o0[j] = (short)f2bf(tile[q * 16 + j][r]);
#pragma unroll
    for (int j = 0; j < 8; j++) o1[j] = (short)f2bf(tile[q * 16 + 8 + j][r]);
    *(s16x8*)dst = o0;
    *(s16x8*)(dst + 8) = o1;
}

// ---------------- projections ----------------
__global__ void proj(const unsigned short* __restrict__ xT, const unsigned short* __restrict__ Wbf,
                     const float* __restrict__ bq, const float* __restrict__ bk,
                     const float* __restrict__ bv,
                     unsigned short* __restrict__ qT, unsigned short* __restrict__ kT,
                     unsigned short* __restrict__ vO) {
    int nt0 = blockIdx.x * 64;
    int mat = blockIdx.y;
    int b   = blockIdx.z;
    int t = threadIdx.x, w = t >> 6, l = t & 63;
    int lr = l & 15, lg = l >> 4;
    const unsigned short* Wm  = Wbf + mat * (Cc * Cc);
    const float* bias = (mat == 0) ? bq : ((mat == 1) ? bk : bv);
    const unsigned short* xTb = xT + (size_t)b * Nn * Cc;

    if (mat < 2) {
        unsigned short* out = ((mat == 0) ? qT : kT) + (size_t)b * Nn * Cc;
        int nrow = nt0 + w * 16;
        s16x8 af[8];
#pragma unroll
        for (int kk = 0; kk < 8; kk++)
            af[kk] = *(const s16x8*)(xTb + (nrow + lr) * Cc + kk * 32 + lg * 8);
        for (int ct = 0; ct < 16; ct++) {
            f32x4 acca = {0, 0, 0, 0}, accb = {0, 0, 0, 0};
#pragma unroll
            for (int kk = 0; kk < 8; kk += 2) {
                s16x8 bfa = *(const s16x8*)(Wm + (ct * 16 + lr) * Cc + kk * 32 + lg * 8);
                s16x8 bfb = *(const s16x8*)(Wm + (ct * 16 + lr) * Cc + (kk + 1) * 32 + lg * 8);
                acca = mfma16(af[kk], bfa, acca);
                accb = mfma16(af[kk + 1], bfb, accb);
            }
            f32x4 acc = acca + accb;
            float bb = bias[ct * 16 + lr];
#pragma unroll
            for (int r = 0; r < 4; r++)
                out[(nrow + lg * 4 + r) * Cc + ct * 16 + lr] = f2bf(acc[r] + bb);
        }
    } else {
        unsigned short* out = vO + (size_t)b * Cc * NV;
        for (int mt = 0; mt < 4; mt++) {
            int crow = (w * 4 + mt) * 16;
            s16x8 af[8];
#pragma unroll
            for (int kk = 0; kk < 8; kk++)
                af[kk] = *(const s16x8*)(Wm + (crow + lr) * Cc + kk * 32 + lg * 8);
#pragma unroll
            for (int nt = 0; nt < 4; nt++) {
                f32x4 acca = {0, 0, 0, 0}, accb = {0, 0, 0, 0};
#pragma unroll
                for (int kk = 0; kk < 8; kk += 2) {
                    s16x8 bfa = *(const s16x8*)(xTb + (nt0 + nt * 16 + lr) * Cc + kk * 32 + lg * 8);
                    s16x8 bfb = *(const s16x8*)(xTb + (nt0 + nt * 16 + lr) * Cc + (kk + 1) * 32 + lg * 8);
                    acca = mfma16(af[kk], bfa, acca);
                    accb = mfma16(af[kk + 1], bfb, accb);
                }
                f32x4 acc = acca + accb;
#pragma unroll
                for (int r = 0; r < 4; r++) {
                    float bb = bias[crow + lg * 4 + r];
                    out[(size_t)(crow + lg * 4 + r) * NV + nt0 + nt * 16 + lr] = f2bf(acc[r] + bb);
                }
            }
        }
    }
}

// ---------------- fused flash attention ----------------
// R10's dataflow (K+V LDS-staged dbuf, S=2 combo-per-XCD, shift-free softmax)
// reshaped for TLP: 512 blocks x 256 thr (4 waves x 16 i-rows = 64 rows/block),
// LDS 68KB -> 2 INDEPENDENT blocks/CU = 2 waves/SIMD that are not barrier-
// coupled: one block's P-roundtrip/drain overlaps the other's MFMA. This is
// the first config where co-resident waves are decorrelated AND not
// V-gather-bound (R7: same-block lockstep; R8: L1 V-gather saturation).
__global__ void __launch_bounds__(256, 2)
attn(const unsigned short* __restrict__ qT, const unsigned short* __restrict__ kT,
     const unsigned short* __restrict__ vv,
     float* __restrict__ OPT, float* __restrict__ lp) {
    int id = blockIdx.x;
    int bs = id & 7, b = bs >> 1, s = bs & 1, iblk = id >> 3;  // iblk 0..63
    int t = threadIdx.x, w = t >> 6, l = t & 63;
    int lr = l & 15, lg = l >> 4;
    int i0 = iblk * 64 + w * 16;

    __shared__ char Ks[2][16384];              // K tile dbuf: 32 rows x 512B
    __shared__ char Vs[2][16384];              // V tile dbuf: 256 rows x 64B
    __shared__ unsigned short P_lds[4][512];   // per-wave [16][32] bf16
    unsigned short* pl = P_lds[w];

    const unsigned short* qb = qT + ((size_t)b * Nn + i0) * Cc;
    const char* kbase = (const char*)(kT + ((size_t)b * Nn + s * 2048) * Cc);
    const char* vbase = (const char*)(vv + (size_t)b * Cc * NV + s * 2048);

    s16x8 qf[8];
#pragma unroll
    for (int kk = 0; kk < 8; kk++)
        qf[kk] = *(const s16x8*)(qb + lr * Cc + kk * 32 + lg * 8);

    f32x4 O[16];
#pragma unroll
    for (int ct = 0; ct < 16; ct++) O[ct] = {0, 0, 0, 0};
    float lsum[4] = {0, 0, 0, 0};
    const float L2E = 1.44269504088896340736f;

// stage 16KB K tile (32 rows x 512B) into Ks[bufi]; wave w covers chunks w*4..w*4+3
#define STAGEK(bufi, jt)                                                        \
    {                                                                           \
        const char* ksl_ = kbase + (size_t)(jt) * 16384;                        \
        _Pragma("unroll") for (int i_ = 0; i_ < 4; i_++) {                      \
            int chunk_ = w * 4 + i_;                                            \
            int L_ = chunk_ * 1024 + l * 16;                                    \
            int row_ = L_ >> 9;                                                 \
            GL16(ksl_ + (L_ ^ ((row_ & 7) << 4)), &Ks[bufi][chunk_ * 1024]);    \
        }                                                                       \
    }

// stage 16KB V tile (256 rows x 64B) into Vs[bufi]; lane l covers row ch*16+(l>>2)
// source col-bytes pre-swizzled by ((row>>1)&3)<<4 = ((l>>3)&3)<<4 per lane
#define STAGEV(bufi, jt)                                                        \
    {                                                                           \
        _Pragma("unroll") for (int i_ = 0; i_ < 4; i_++) {                      \
            int chunk_ = w * 4 + i_;                                            \
            int row_ = chunk_ * 16 + (l >> 2);                                  \
            int colb_ = ((l & 3) * 16) ^ (((l >> 3) & 3) << 4);                 \
            GL16(vbase + (size_t)row_ * (NV * 2) + (size_t)(jt) * 64 + colb_,   \
                 &Vs[bufi][chunk_ * 1024]);                                     \
        }                                                                       \
    }

    STAGEK(0, 0);
    STAGEV(0, 0);
    asm volatile("s_waitcnt vmcnt(0)" ::: "memory");
    __syncthreads();
    int buf = 0;

    for (int jt = 0; jt < 64; jt++) {
        // ---- prefetch next K+V tiles into other buffer ----
        if (jt < 63) {
            STAGEK(buf ^ 1, jt + 1);
            STAGEV(buf ^ 1, jt + 1);
        }
        // ---- QK^T from K-LDS ----
        const char* ksb = Ks[buf];
        f32x4 E0 = {0, 0, 0, 0}, E1 = {0, 0, 0, 0};
#pragma unroll
        for (int kk = 0; kk < 8; kk++) {
            int cb = (kk * 64 + lg * 16) ^ ((lr & 7) << 4);
            s16x8 k0 = *(const s16x8*)(ksb + lr * 512 + cb);
            s16x8 k1 = *(const s16x8*)(ksb + (16 + lr) * 512 + cb);
            E0 = mfma16(qf[kk], k0, E0);
            E1 = mfma16(qf[kk], k1, E1);
        }
        // ---- shift-free softmax ----
        float p0[4], p1[4];
#pragma unroll
        for (int r = 0; r < 4; r++) {
            p0[r] = exp2f(E0[r] * L2E);
            p1[r] = exp2f(E1[r] * L2E);
            lsum[r] += p0[r] + p1[r];
        }
        // ---- P -> bf16 -> LDS (wave-synchronous roundtrip) ----
#pragma unroll
        for (int r = 0; r < 4; r++) {
            pl[(lg * 4 + r) * 32 + lr] = f2bf(p0[r]);
            pl[(lg * 4 + r) * 32 + 16 + lr] = f2bf(p1[r]);
        }
        // ---- V reads issued before the drain (latency absorbed together) ----
        const char* vsb = Vs[buf];
        int vswz = (lg * 16) ^ (((lr >> 1) & 3) << 4);
        s16x8 vfr[16];
#pragma unroll
        for (int ct = 0; ct < 16; ct++)
            vfr[ct] = *(const s16x8*)(vsb + (ct * 16 + lr) * 64 + vswz);
        asm volatile("s_waitcnt lgkmcnt(0)" ::: "memory");
        __builtin_amdgcn_sched_barrier(0);
        s16x8 pf = *(const s16x8*)(pl + lr * 32 + lg * 8);
        // ---- PV ----
#pragma unroll
        for (int ct = 0; ct < 16; ct++)
            O[ct] = mfma16(pf, vfr[ct], O[ct]);
        asm volatile("s_waitcnt vmcnt(0)" ::: "memory");
        __syncthreads();
        buf ^= 1;
    }

    // ---- l reduction across 16 lanes of each row group ----
#pragma unroll
    for (int r = 0; r < 4; r++) {
#pragma unroll
        for (int msk = 1; msk <= 8; msk <<= 1)
            lsum[r] += __shfl_xor(lsum[r], msk);
    }
    size_t sb = (size_t)(s * Bb + b);
    if (lr == 0) {
#pragma unroll
        for (int r = 0; r < 4; r++)
            lp[sb * Nn + i0 + lg * 4 + r] = lsum[r];
    }
    // ---- fp32 partials, [n][c] layout ----
    float* ob = OPT + sb * Nn * Cc;
#pragma unroll
    for (int ct = 0; ct < 16; ct++) {
#pragma unroll
        for (int r = 0; r < 4; r++)
            ob[(size_t)(i0 + lg * 4 + r) * Cc + ct * 16 + lr] = O[ct][r];
    }
#undef STAGEK
#undef STAGEV
}

// ---------------- merge partials + transpose + epilogue ----------------
// out[b][c][n] = gamma * (OPT0+OPT1)[n][c] / (l0+l1)[n] + x[b][c][n]
__global__ void __launch_bounds__(256)
merge(const float* __restrict__ OPT, const float* __restrict__ lp,
      const float* __restrict__ x, const float* __restrict__ gamma,
      float* __restrict__ out) {
    int b = blockIdx.z, c0 = blockIdx.y * 64, n0 = blockIdx.x * 64;
    __shared__ float tile[64][65];
    __shared__ float linv[64];
    int t = threadIdx.x;
    if (t < 64) {
        float sum = lp[(size_t)b * Nn + n0 + t] + lp[(size_t)(Bb + b) * Nn + n0 + t];
        linv[t] = 1.0f / sum;
    }
    __syncthreads();
    float g = gamma[0];
    int r = t >> 2, q = t & 3;
    const float* p0 = OPT + ((size_t)b * Nn + n0 + r) * Cc + c0 + q * 16;
    const float* p1 = OPT + ((size_t)(Bb + b) * Nn + n0 + r) * Cc + c0 + q * 16;
    float sc = g * linv[r];
#pragma unroll
    for (int j = 0; j < 4; j++) {
        float4 a0 = *(const float4*)(p0 + j * 4);
        float4 a1 = *(const float4*)(p1 + j * 4);
        tile[r][q * 16 + j * 4 + 0] = sc * (a0.x + a1.x);
        tile[r][q * 16 + j * 4 + 1] = sc * (a0.y + a1.y);
        tile[r][q * 16 + j * 4 + 2] = sc * (a0.z + a1.z);
        tile[r][q * 16 + j * 4 + 3] = sc * (a0.w + a1.w);
    }
    __syncthreads();
    const float* xp = x + ((size_t)b * Cc + c0 + r) * Nn + n0 + q * 16;
    float* op = out + ((size_t)b * Cc + c0 + r) * Nn + n0 + q * 16;
#pragma unroll
    for (int j = 0; j < 4; j++) {
        float4 xv = *(const float4*)(xp + j * 4);
        float4 o4;
        o4.x = tile[q * 16 + j * 4 + 0][r] + xv.x;
        o4.y = tile[q * 16 + j * 4 + 1][r] + xv.y;
        o4.z = tile[q * 16 + j * 4 + 2][r] + xv.z;
        o4.w = tile[q * 16 + j * 4 + 3][r] + xv.w;
        *(float4*)(op + j * 4) = o4;
    }
}

extern "C" void kernel_launch(void* const* d_in, const int* in_sizes, int n_in,
                              void* d_out, int out_size, void* d_ws, size_t ws_size,
                              hipStream_t stream) {
    (void)in_sizes; (void)n_in; (void)out_size; (void)ws_size;
    const float* x     = (const float*)d_in[0];
    const float* Wq    = (const float*)d_in[1];
    const float* bq    = (const float*)d_in[2];
    const float* Wk    = (const float*)d_in[3];
    const float* bk    = (const float*)d_in[4];
    const float* Wv    = (const float*)d_in[5];
    const float* bv    = (const float*)d_in[6];
    const float* gamma = (const float*)d_in[7];
    float* out = (float*)d_out;

    const size_t XTN = (size_t)Bb * Nn * Cc;   // 4,194,304 elements
    const size_t VSZ = (size_t)Bb * Cc * NV;   // padded V
    unsigned short* xT  = (unsigned short*)d_ws;
    unsigned short* Wbf = xT + XTN;
    unsigned short* qT  = Wbf + 3 * Cc * Cc;
    unsigned short* kT  = qT + XTN;
    unsigned short* vv  = kT + XTN;
    float*          OPT = (float*)(vv + VSZ);        // 2 * XTN fp32 = 32MB
    float*          lp  = OPT + 2 * XTN;             // 2*B*N fp32

    hipLaunchKernelGGL(prep_w, dim3(96), dim3(256), 0, stream, Wq, Wk, Wv, Wbf);
    hipLaunchKernelGGL(transpose_x, dim3(Nn / 64, Cc / 64, Bb), dim3(256), 0, stream, x, xT);
    hipLaunchKernelGGL(proj, dim3(Nn / 64, 3, Bb), dim3(256), 0, stream,
                       xT, Wbf, bq, bk, bv, qT, kT, vv);
    hipLaunchKernelGGL(attn, dim3(512), dim3(256), 0, stream,
                       qT, kT, vv, OPT, lp);
    hipLaunchKernelGGL(merge, dim3(Nn / 64, Cc / 64, Bb), dim3(256), 0, stream,
                       OPT, lp, x, gamma, out);
}